// Round 4
// baseline (1255.259 us; speedup 1.0000x reference)
//
#include <hip/hip_runtime.h>
#include <math.h>

#define N_EMBD 768
#define N_EXP  8
#define DIMH   2048
#define CAPN   1024
#define M_TOT  8192

typedef __bf16 bf16x8 __attribute__((ext_vector_type(8)));
typedef float  f32x4  __attribute__((ext_vector_type(4)));
typedef unsigned short u16x4 __attribute__((ext_vector_type(4)));

__device__ __forceinline__ unsigned short f2bf(float f) {
    unsigned int u = __float_as_uint(f);
    unsigned int r = (u + 0x7fffu + ((u >> 16) & 1u)) >> 16;
    return (unsigned short)r;
}

__device__ __forceinline__ void gload16(const void* g, void* l) {
    __builtin_amdgcn_global_load_lds(
        (const __attribute__((address_space(1))) unsigned int*)g,
        (__attribute__((address_space(3))) unsigned int*)l, 16, 0, 0);
}

// branch-free exact-gelu: erf via A&S 7.1.26 (|err|<1.5e-7, sub-bf16-ulp)
__device__ __forceinline__ float gelu_exact(float x) {
    float ax = fabsf(x);
    float z  = ax * 0.70710678118654752f;
    float t  = __builtin_amdgcn_rcpf(fmaf(0.3275911f, z, 1.0f));
    float p  = fmaf(t, 1.061405429f, -1.453152027f);
    p = fmaf(p, t, 1.421413741f);
    p = fmaf(p, t, -0.284496736f);
    p = fmaf(p, t, 0.254829592f);
    p = p * t;
    float ez = __expf(-z * z);
    float erfz = fmaf(-p, ez, 1.0f);
    return 0.5f * fmaf(ax, erfz, x);
}

// ---------------------------------------------------------------------------
// Kernel A: per-row L2 norm + scale + gamma + fp32->bf16.  One WAVE per row.
// ---------------------------------------------------------------------------
__global__ __launch_bounds__(256) void norm_convert_kernel(
        const float* __restrict__ x, const float* __restrict__ gamma,
        unsigned short* __restrict__ h) {
    int r = (blockIdx.x << 2) | (threadIdx.x >> 6);   // row 0..65535
    int lane = threadIdx.x & 63;
    int e = r >> 13, m = r & 8191;
    int b = m >> 10, nc = m & 1023;
    const float4* row = (const float4*)(x + (size_t)((b * N_EXP + e) * CAPN + nc) * N_EMBD);
    const float4* g4  = (const float4*)gamma;

    float4 v0 = row[lane], v1 = row[lane + 64], v2 = row[lane + 128];
    float acc = v0.x*v0.x + v0.y*v0.y + v0.z*v0.z + v0.w*v0.w
              + v1.x*v1.x + v1.y*v1.y + v1.z*v1.z + v1.w*v1.w
              + v2.x*v2.x + v2.y*v2.y + v2.z*v2.z + v2.w*v2.w;
#pragma unroll
    for (int off = 32; off >= 1; off >>= 1) acc += __shfl_xor(acc, off, 64);
    float s = 27.712812921102035f / fmaxf(sqrtf(acc), 1e-12f);

    float4 g0 = g4[lane], g1 = g4[lane + 64], g2 = g4[lane + 128];
    u16x4* o4 = (u16x4*)(h + (size_t)(e * M_TOT + m) * N_EMBD);
    u16x4 o;
    o[0]=f2bf(v0.x*s*g0.x); o[1]=f2bf(v0.y*s*g0.y); o[2]=f2bf(v0.z*s*g0.z); o[3]=f2bf(v0.w*s*g0.w);
    o4[lane] = o;
    o[0]=f2bf(v1.x*s*g1.x); o[1]=f2bf(v1.y*s*g1.y); o[2]=f2bf(v1.z*s*g1.z); o[3]=f2bf(v1.w*s*g1.w);
    o4[lane + 64] = o;
    o[0]=f2bf(v2.x*s*g2.x); o[1]=f2bf(v2.y*s*g2.y); o[2]=f2bf(v2.z*s*g2.z); o[3]=f2bf(v2.w*s*g2.w);
    o4[lane + 128] = o;
}

// ---------------------------------------------------------------------------
// Kernel B: transpose + convert weights. in: [z][R][C] fp32 -> out: [z][C][R] bf16
// ---------------------------------------------------------------------------
__global__ __launch_bounds__(256) void transpose_convert_kernel(
        const float* __restrict__ in, unsigned short* __restrict__ out, int R, int C) {
    __shared__ float tile[32][33];
    int c0 = blockIdx.x * 32, r0 = blockIdx.y * 32;
    const float* ip = in + (size_t)blockIdx.z * R * C;
    unsigned short* op = out + (size_t)blockIdx.z * R * C;
    int tx = threadIdx.x & 31, ty = threadIdx.x >> 5;
#pragma unroll
    for (int i = 0; i < 4; ++i)
        tile[ty + 8 * i][tx] = ip[(size_t)(r0 + ty + 8 * i) * C + c0 + tx];
    __syncthreads();
#pragma unroll
    for (int i = 0; i < 4; ++i)
        op[(size_t)(c0 + ty + 8 * i) * R + r0 + tx] = f2bf(tile[tx][ty + 8 * i]);
}

// ---------------------------------------------------------------------------
// 2-phase-per-K-tile 256-row GEMM machinery (32-MFMA clusters, counted vmcnt).
// Every vmcnt gate precedes (with >=1 barrier) the ds_reads of the data it
// forces. Every LDS region is restaged >=1 full phase after its last read.
// ---------------------------------------------------------------------------
#define BAR   __builtin_amdgcn_s_barrier()
#define SB0   __builtin_amdgcn_sched_barrier(0)
#define PRIO1 __builtin_amdgcn_s_setprio(1)
#define PRIO0 __builtin_amdgcn_s_setprio(0)
#define LKW(N) do { asm volatile("s_waitcnt lgkmcnt(" #N ")" ::: "memory"); SB0; } while (0)
#define VMW(N) do { asm volatile("s_waitcnt vmcnt(" #N ")" ::: "memory"); SB0; } while (0)

// stage one 128x64 half-tile: 512 thr x 2 loads x 16B; linear LDS dest,
// inverse-swizzled global source. KO = k offset in elements.
#define STG2(PSRC, RS, KO, DOFF) do { \
    gload16((PSRC) + (size_t)sr * (RS) + (KO) + scs, lds + (DOFF) + ldst); \
    gload16((PSRC) + (size_t)(sr + 64) * (RS) + (KO) + scs, lds + (DOFF) + ldst + 4096); \
  } while (0)

#define RDF(V) (*(const bf16x8*)(lds + (V)))

#define RDA4(AF, DB, IB) do { \
    _Pragma("unroll") for (int i_ = 0; i_ < 4; ++i_) { \
      AF[i_][0] = RDF((DB)*32768 + aB + ((IB) + i_)*1024 + sl0); \
      AF[i_][1] = RDF((DB)*32768 + aB + ((IB) + i_)*1024 + sl1); } \
  } while (0)

#define RDB2(BF, DB, BASE) do { \
    _Pragma("unroll") for (int j_ = 0; j_ < 2; ++j_) { \
      BF[j_][0] = RDF((DB)*32768 + (BASE) + j_*1024 + sl0); \
      BF[j_][1] = RDF((DB)*32768 + (BASE) + j_*1024 + sl1); } \
  } while (0)

#define QUAD(ACC, MS, NB, AF, BF) do { \
    _Pragma("unroll") for (int i_ = 0; i_ < 4; ++i_) \
    _Pragma("unroll") for (int j_ = 0; j_ < 2; ++j_) { \
      ACC[(MS)*4 + i_][(NB) + j_] = __builtin_amdgcn_mfma_f32_16x16x32_bf16( \
          AF[i_][0], BF[j_][0], ACC[(MS)*4 + i_][(NB) + j_], 0, 0, 0); \
      ACC[(MS)*4 + i_][(NB) + j_] = __builtin_amdgcn_mfma_f32_16x16x32_bf16( \
          AF[i_][1], BF[j_][1], ACC[(MS)*4 + i_][(NB) + j_], 0, 0, 0); } \
  } while (0)

// ---------------------------------------------------------------------------
// Kernel C: GEMM1 + GLU epilogue. Block tile 256(M) x 128(g-cols), BK=64.
// Iter J = K-tiles E=2J (dbuf0), O=2J+1 (dbuf1); 4 phases, 32 MFMA each.
//   Ph1: read E.{bv,a0-7}; stage O.Bg;            MFMA accv(E)
//   Ph2: read E.bg; stage E'.{Bv,A0,A1}; VMW(6)   MFMA accg(E)   [forces O]
//   Ph3: read O.{bv,a0-7}; stage E'.Bg;           MFMA accv(O)
//   Ph4: read O.bg; stage O'.{Bv,A0,A1}; VMW(6)   MFMA accg(O)   [forces E']
// Ledger (steady, 2 loads/half-tile): enter Ph1 with 6 in flight.
//   Ph1 +2=8; Ph2 +6=14, gate 6 -> 8 remain (E'.Bv,A0,A1 partial... = E'? no:
//   forces 8 oldest = O full; remain 6; Ph3 +2=8; Ph4 +6=14, gate 6 -> 6. OK.
// ---------------------------------------------------------------------------
__global__ __launch_bounds__(512, 2) void gemm1_kernel(
        const unsigned short* __restrict__ hb,   // [E][8192][768]
        const unsigned short* __restrict__ fT,   // [E][4096][768]
        const float* __restrict__ mbias,         // [2048]
        unsigned short* __restrict__ gb,         // [z][8192][2048]
        int e0) {
    __shared__ __align__(16) unsigned short lds[65536];   // 128 KiB
    const int t = threadIdx.x;
    const int e = e0 + blockIdx.z;
    const int m0 = blockIdx.x * 256;
    const int n0 = blockIdx.y * 128;
    const unsigned short* pA  = hb + ((size_t)e * M_TOT + m0) * N_EMBD;
    const unsigned short* pBv = fT + ((size_t)e * 2 * DIMH + n0) * N_EMBD;
    const unsigned short* pBg = pBv + (size_t)DIMH * N_EMBD;
    unsigned short* pG = gb + (size_t)blockIdx.z * M_TOT * DIMH;

    const int sr   = t >> 3;
    const int scs  = ((t & 7) ^ (sr & 7)) * 8;
    const int ldst = t * 8;
    const int lane = t & 63, lo = lane & 15, quad = lane >> 4;
    const int w = t >> 6, wm = w & 1, wn = w >> 1;
    const int sl0 = ((quad    ) ^ (lo & 7)) * 8;
    const int sl1 = ((quad + 4) ^ (lo & 7)) * 8;
    const int aB  = wm * 8192 + lo * 64;
    const int bvB = 16384 + (wn * 32 + lo) * 64;
    const int bgB = 24576 + (wn * 32 + lo) * 64;

#define STA1(D, H, KO)  STG2(pA + (size_t)(H) * 128 * N_EMBD, N_EMBD, KO, (D)*32768 + (H)*8192)
#define STBV1(D, KO)    STG2(pBv, N_EMBD, KO, (D)*32768 + 16384)
#define STBG1(D, KO)    STG2(pBg, N_EMBD, KO, (D)*32768 + 24576)

    f32x4 accv[8][2], accg[8][2];
#pragma unroll
    for (int i = 0; i < 8; ++i)
#pragma unroll
        for (int j = 0; j < 2; ++j) { accv[i][j] = (f32x4)0.f; accg[i][j] = (f32x4)0.f; }
    bf16x8 a0[4][2], a1[4][2], bv[2][2], bg[2][2];

    // prologue: t0 full (oldest) + t1.{Bv,A0,A1}; force t0, 6 stay in flight
    STBV1(0, 0); STA1(0, 0, 0); STA1(0, 1, 0); STBG1(0, 0);
    STBV1(1, 64); STA1(1, 0, 64); STA1(1, 1, 64);
    VMW(6);
    BAR;

    for (int it = 0; it < 6; ++it) {                 // 12 K-tiles, 2 per iter
        const bool more = (it < 5);
        const int koO  = it * 128 + 64;              // tile 2it+1
        const int koE2 = it * 128 + 128;             // tile 2it+2
        const int koO2 = it * 128 + 192;             // tile 2it+3
        // ---- Ph1: E accv ----
        RDB2(bv, 0, bvB); RDA4(a0, 0, 0);
        SB0;                                         // pin group1 | group2 order
        RDA4(a1, 0, 4);
        STBG1(1, koO);                               // O.Bg (d1.Bg free since prev Ph4)
        BAR; LKW(8); PRIO1;                          // group1 ready, a1 may lag
        QUAD(accv, 0, 0, a0, bv);
        LKW(0);
        QUAD(accv, 1, 0, a1, bv);
        PRIO0; BAR;
        // ---- Ph2: E accg; gate O ----
        RDB2(bg, 0, bgB);
        if (more) { STBV1(0, koE2); STA1(0, 0, koE2); STA1(0, 1, koE2); VMW(6); }
        else      { VMW(0); }
        BAR; LKW(0); PRIO1;
        QUAD(accg, 0, 0, a0, bg);
        QUAD(accg, 1, 0, a1, bg);
        PRIO0; BAR;
        // ---- Ph3: O accv ----
        RDB2(bv, 1, bvB); RDA4(a0, 1, 0);
        SB0;
        RDA4(a1, 1, 4);
        if (more) STBG1(0, koE2);                    // E'.Bg (d0.Bg free since Ph2)
        BAR; LKW(8); PRIO1;
        QUAD(accv, 0, 0, a0, bv);
        LKW(0);
        QUAD(accv, 1, 0, a1, bv);
        PRIO0; BAR;
        // ---- Ph4: O accg; gate E' ----
        RDB2(bg, 1, bgB);
        if (more) { STBV1(1, koO2); STA1(1, 0, koO2); STA1(1, 1, koO2); VMW(6); }
        BAR; LKW(0); PRIO1;
        QUAD(accg, 0, 0, a0, bg);
        QUAD(accg, 1, 0, a1, bg);
        PRIO0; BAR;
    }

    // epilogue: g = gelu_exact(gate) * v * mbias (C/D: col=lane&15, row=quad*4+r)
#pragma unroll
    for (int i = 0; i < 8; ++i) {
        const int mb = m0 + wm * 128 + i * 16 + quad * 4;
#pragma unroll
        for (int j = 0; j < 2; ++j) {
            const int n = n0 + wn * 32 + j * 16 + lo;
            const float mbv = mbias[n];
#pragma unroll
            for (int r = 0; r < 4; ++r) {
                float ge = gelu_exact(accg[i][j][r]);
                pG[(size_t)(mb + r) * DIMH + n] = f2bf(ge * accv[i][j][r] * mbv);
            }
        }
    }
#undef STA1
#undef STBV1
#undef STBG1
}

// ---------------------------------------------------------------------------
// Kernel D: GEMM2, one block per (m-tile, expert) = 256 blocks (1/CU).
// Loops the 3 n-tiles (n0 = 0,256,512) INSIDE the block: A (g-buffer) is
// fetched from HBM once and re-staged L2-hot; B per expert is L2/L3-hot.
// Per pass: tile 256x256, BK=64, 32 K-tiles, 2 phases per K-tile:
//   Ph1: read E.{bbL,bbH,a0}; stage O.{A0,A1};          MFMA a0 x bb
//   Ph2: read E.a1; stage E'.{B0,B1}; VMW(4) [forces O] MFMA a1 x bb
//   Ph3: read O.{bbL,bbH,a0}; stage E'.{A0,A1};         MFMA a0 x bb
//   Ph4: read O.a1; stage O'.{B0,B1}; VMW(4) [forces E'] MFMA a1 x bb
// Ledger: enter Ph1 with 4 (O.B); +4=8; +4=12 gate4; +4=8... -> steady 4. OK.
// ---------------------------------------------------------------------------
__global__ __launch_bounds__(512, 2) void gemm2_kernel(
        const unsigned short* __restrict__ gb,   // [z][8192][2048]
        const unsigned short* __restrict__ pT,   // [E][768][2048]
        float* __restrict__ out, int e0) {
    __shared__ __align__(16) unsigned short lds[65536];
    const int t = threadIdx.x;
    const int e = e0 + blockIdx.z;
    const int m0 = blockIdx.x * 256;
    const unsigned short* pA = gb + (size_t)blockIdx.z * M_TOT * DIMH + (size_t)m0 * DIMH;

    const int sr   = t >> 3;
    const int scs  = ((t & 7) ^ (sr & 7)) * 8;
    const int ldst = t * 8;
    const int lane = t & 63, lo = lane & 15, quad = lane >> 4;
    const int w = t >> 6, wm = w & 1, wn = w >> 1;
    const int sl0 = ((quad    ) ^ (lo & 7)) * 8;
    const int sl1 = ((quad + 4) ^ (lo & 7)) * 8;
    const int aB  = wm * 8192 + lo * 64;
    const int bB  = 16384 + (wn >> 1) * 8192 + ((wn & 1) * 64 + lo) * 64;

#define STA2(D, H, KO)  STG2(pA + (size_t)(H) * 128 * DIMH, DIMH, KO, (D)*32768 + (H)*8192)
#define STB2(D, H, KO)  STG2(pB + (size_t)(H) * 128 * DIMH, DIMH, KO, (D)*32768 + 16384 + (H)*8192)

    bf16x8 a0[4][2], a1[4][2], bbL[2][2], bbH[2][2];

    for (int yp = 0; yp < 3; ++yp) {
        const int n0 = yp * 256;
        const unsigned short* pB = pT + ((size_t)e * N_EMBD + n0) * DIMH;

        f32x4 acc[8][4];
#pragma unroll
        for (int i = 0; i < 8; ++i)
#pragma unroll
            for (int j = 0; j < 4; ++j) acc[i][j] = (f32x4)0.f;

        // prologue: t0.{B,A} (oldest) + t1.B; force t0, 4 stay in flight
        STB2(0, 0, 0); STB2(0, 1, 0); STA2(0, 0, 0); STA2(0, 1, 0);
        STB2(1, 0, 64); STB2(1, 1, 64);
        VMW(4);
        BAR;

        for (int it = 0; it < 16; ++it) {            // 32 K-tiles, 2 per iter
            const bool more = (it < 15);
            const int koO  = it * 128 + 64;
            const int koE2 = it * 128 + 128;
            const int koO2 = it * 128 + 192;
            // ---- Ph1 ----
            RDB2(bbL, 0, bB); RDB2(bbH, 0, bB + 2048); RDA4(a0, 0, 0);
            STA2(1, 0, koO); STA2(1, 1, koO);        // O.A (d1.A free since prev Ph4)
            BAR; LKW(0); PRIO1;
            QUAD(acc, 0, 0, a0, bbL);
            QUAD(acc, 0, 2, a0, bbH);
            PRIO0; BAR;
            // ---- Ph2: gate O ----
            RDA4(a1, 0, 4);
            if (more) { STB2(0, 0, koE2); STB2(0, 1, koE2); VMW(4); }
            else      { VMW(0); }
            BAR; LKW(0); PRIO1;
            QUAD(acc, 1, 0, a1, bbL);
            QUAD(acc, 1, 2, a1, bbH);
            PRIO0; BAR;
            // ---- Ph3 ----
            RDB2(bbL, 1, bB); RDB2(bbH, 1, bB + 2048); RDA4(a0, 1, 0);
            if (more) { STA2(0, 0, koE2); STA2(0, 1, koE2); }
            BAR; LKW(0); PRIO1;
            QUAD(acc, 0, 0, a0, bbL);
            QUAD(acc, 0, 2, a0, bbH);
            PRIO0; BAR;
            // ---- Ph4: gate E' ----
            RDA4(a1, 1, 4);
            if (more) { STB2(1, 0, koO2); STB2(1, 1, koO2); VMW(4); }
            BAR; LKW(0); PRIO1;
            QUAD(acc, 1, 0, a1, bbL);
            QUAD(acc, 1, 2, a1, bbH);
            PRIO0; BAR;
        }

        // epilogue: scatter fp32 rows to (B, E, CAP, D)
#pragma unroll
        for (int i = 0; i < 8; ++i) {
            const int mb = m0 + wm * 128 + i * 16 + quad * 4;
#pragma unroll
            for (int r = 0; r < 4; ++r) {
                const int m = mb + r;
                const int b = m >> 10, nc = m & 1023;
                float* orow = out + (size_t)((b * N_EXP + e) * CAPN + nc) * N_EMBD;
#pragma unroll
                for (int j = 0; j < 4; ++j)
                    orow[n0 + wn * 64 + j * 16 + lo] = acc[i][j][r];
            }
        }
    }
#undef STA2
#undef STB2
}

// ---------------------------------------------------------------------------
extern "C" void kernel_launch(void* const* d_in, const int* in_sizes, int n_in,
                              void* d_out, int out_size, void* d_ws, size_t ws_size,
                              hipStream_t stream) {
    const float* x     = (const float*)d_in[0];
    const float* cfc   = (const float*)d_in[1];
    const float* cproj = (const float*)d_in[2];
    const float* gamma = (const float*)d_in[3];
    const float* mbias = (const float*)d_in[4];
    float* out = (float*)d_out;

    unsigned short* h      = (unsigned short*)d_ws;
    unsigned short* cfcT   = h + 50331648ull;
    unsigned short* cprojT = cfcT + 25165824ull;
    unsigned short* gbuf   = cprojT + 12582912ull;
    const size_t need_batched = 444596224ull;   // bytes

    norm_convert_kernel<<<dim3(N_EXP * M_TOT / 4), dim3(256), 0, stream>>>(x, gamma, h);
    transpose_convert_kernel<<<dim3(2 * DIMH / 32, N_EMBD / 32, N_EXP), dim3(256), 0, stream>>>(
        cfc, cfcT, N_EMBD, 2 * DIMH);
    transpose_convert_kernel<<<dim3(N_EMBD / 32, DIMH / 32, N_EXP), dim3(256), 0, stream>>>(
        cproj, cprojT, DIMH, N_EMBD);

    if (ws_size >= need_batched) {
        gemm1_kernel<<<dim3(M_TOT / 256, DIMH / 128, N_EXP), dim3(512), 0, stream>>>(
            h, cfcT, mbias, gbuf, 0);
        gemm2_kernel<<<dim3(M_TOT / 256, 1, N_EXP), dim3(512), 0, stream>>>(
            gbuf, cprojT, out, 0);
    } else {
        for (int e = 0; e < N_EXP; ++e) {
            gemm1_kernel<<<dim3(M_TOT / 256, DIMH / 128, 1), dim3(512), 0, stream>>>(
                h, cfcT, mbias, gbuf, e);
            gemm2_kernel<<<dim3(M_TOT / 256, 1, 1), dim3(512), 0, stream>>>(
                gbuf, cprojT, out, e);
        }
    }
}